// Round 14
// baseline (1052.868 us; speedup 1.0000x reference)
//
#include <hip/hip_runtime.h>
#include <hip/hip_bf16.h>
#include <math.h>

#define TP 257
#define ROWS 2056          // B * (SEQ+1)
#define XDIM 2048          // bf16 state row: [relu 1024 | ln 512 | attn 256 | u 256]
#define ZDIM 1792          // RELU_DIM + LN_DIM + DIM (classifier width)
#define PREDIM 1536
#define QKVDIM 768
#define EMBD 256

using f32x4  = __attribute__((ext_vector_type(4))) float;
using bf16x8 = __attribute__((ext_vector_type(8))) short;

__device__ __forceinline__ ushort f2bf(float f) {
    uint32_t u = __float_as_uint(f);
    return (ushort)((u + 0x7fffu + ((u >> 16) & 1u)) >> 16);   // RNE
}
__device__ __forceinline__ float bf2f(ushort u) {
    return __uint_as_float(((uint32_t)u) << 16);
}

#define GLD16(g, l) __builtin_amdgcn_global_load_lds( \
    (const __attribute__((address_space(1))) void*)(g), \
    (__attribute__((address_space(3))) void*)(l), 16, 0, 0)

// ---------------------------------------------------------------------------
// fp32 -> bf16 weight conversion (once per call)
// ---------------------------------------------------------------------------
__global__ __launch_bounds__(256) void f2bf_kernel(
    const float* __restrict__ in, ushort* __restrict__ out, int n)
{
    int i = blockIdx.x * 256 + threadIdx.x;
    if (i < n) out[i] = f2bf(in[i]);
}

// ---------------------------------------------------------------------------
// u-columns (1792..2047) of BOTH state buffers
// ---------------------------------------------------------------------------
__global__ __launch_bounds__(256) void build_u_kernel(
    const int* __restrict__ x, const float* __restrict__ emb,
    const float* __restrict__ cls, ushort* __restrict__ xbA, ushort* __restrict__ xbB)
{
    int row = blockIdx.x;
    int e   = threadIdx.x;
    int b = row / TP, t = row % TP;
    float val;
    if (t == 0) {
        val = cls[e];
    } else {
        int tt = t - 1;
        int xi = x[b * 256 + tt];
        float ang = (float)tt * expf(-(float)(e & ~1) * 0.035978672652993f);
        float pe  = (e & 1) ? cosf(ang) : sinf(ang);
        val = emb[(size_t)xi * EMBD + e] + pe;
    }
    ushort bv = f2bf(val);
    xbA[(size_t)row * XDIM + 1792 + e] = bv;
    xbB[(size_t)row * XDIM + 1792 + e] = bv;
}

// ---------------------------------------------------------------------------
// C(MxN) = X(MxK bf16) @ W(NxK bf16)^T (+ bias). fp32 out (C) or bf16 (Cb).
// m97 inner geometry (128x128 tile, 4 waves, 4x4 16x16x32 frags, BK=32) +
// T3-minimum double-buffered prefetch: STAGE(next) -> ds_read(cur)+MFMA ->
// barrier (compiler's vmcnt(0)-before-barrier drains a load issued BEFORE
// compute, so per-K-step cost ~ max(load_lat, compute), not the sum).
// Split-K over blockIdx.z; fp32 partials at C + z*splitStride; bias from z==0.
// ---------------------------------------------------------------------------
__global__ __launch_bounds__(256) void gemm_bf16_kernel(
    const ushort* __restrict__ X, int ldx,
    const ushort* __restrict__ W,          // [N][Ktotal]
    const float* __restrict__ bias,
    float* __restrict__ C, ushort* __restrict__ Cb,
    int ldc, int M, int N, int Ksplit, int Ktotal, size_t splitStride)
{
    __shared__ ushort As[2][128 * 32];
    __shared__ ushort Bs[2][128 * 32];
    int tid  = threadIdx.x;
    int lane = tid & 63, wv = tid >> 6;
    int wr = wv >> 1, wc = wv & 1;
    int r0 = blockIdx.x * 128, c0 = blockIdx.y * 128;
    int kbeg = blockIdx.z * Ksplit;
    int kfin = kbeg + Ksplit;

    f32x4 acc[4][4] = {};

    int srow = wv * 32 + (lane >> 2);
    int skol = (lane & 3) * 8;
    int fk   = (lane >> 4) * 8;

    auto stage = [&](int buf, int k0) {
        #pragma unroll
        for (int i = 0; i < 2; ++i) {
            int rr = r0 + srow + i * 16;
            if (rr >= M) rr = M - 1;                    // clamp: harmless dup rows
            const ushort* ga = X + (size_t)rr * ldx + k0 + skol;
            GLD16(ga, &As[buf][(wv * 32 + i * 16) * 32]);
            const ushort* gb = W + (size_t)(c0 + srow + i * 16) * Ktotal + k0 + skol;
            GLD16(gb, &Bs[buf][(wv * 32 + i * 16) * 32]);
        }
    };

    stage(0, kbeg);
    __syncthreads();                        // vmcnt(0) drain + barrier
    int cur = 0;

    for (int k0 = kbeg; k0 < kfin; k0 += 32) {
        if (k0 + 32 < kfin) stage(cur ^ 1, k0 + 32);   // prefetch next tile

        bf16x8 a[4], b[4];
        #pragma unroll
        for (int m = 0; m < 4; ++m)
            a[m] = *(const bf16x8*)&As[cur][(wr * 64 + m * 16 + (lane & 15)) * 32 + fk];
        #pragma unroll
        for (int n = 0; n < 4; ++n)
            b[n] = *(const bf16x8*)&Bs[cur][(wc * 64 + n * 16 + (lane & 15)) * 32 + fk];
        #pragma unroll
        for (int m = 0; m < 4; ++m)
            #pragma unroll
            for (int n = 0; n < 4; ++n)
                acc[m][n] = __builtin_amdgcn_mfma_f32_16x16x32_bf16(a[m], b[n], acc[m][n], 0, 0, 0);

        __syncthreads();                    // drains prefetch; orders buf reuse
        cur ^= 1;
    }

    // epilogue: D col = lane&15, row = (lane>>4)*4 + j   [m89/m91-verified]
    int crow = (lane >> 4) * 4;
    int ccol = lane & 15;
    float* Cz = C ? C + (size_t)blockIdx.z * splitStride : nullptr;
    bool addb = (bias != nullptr) && (blockIdx.z == 0);
    #pragma unroll
    for (int m = 0; m < 4; ++m) {
        #pragma unroll
        for (int j = 0; j < 4; ++j) {
            int r = r0 + wr * 64 + m * 16 + crow + j;
            if (r < M) {
                #pragma unroll
                for (int n = 0; n < 4; ++n) {
                    int cc = n * 16 + ccol;
                    float vb = addb ? bias[c0 + wc * 64 + cc] : 0.0f;
                    float v = acc[m][n][j] + vb;
                    if (Cb) Cb[(size_t)r * ldc + c0 + wc * 64 + cc] = f2bf(v);
                    else    Cz[(size_t)r * ldc + c0 + wc * 64 + cc] = v;
                }
            }
        }
    }
}

// ---------------------------------------------------------------------------
// z[:, :1024] = relu(sum pre_s); z[:, 1024:1536] = LN_256(sum pre_s) -> bf16
// nsplit fp32 partial buffers at stride splitStride. float4 vectorized.
// ---------------------------------------------------------------------------
__global__ __launch_bounds__(256) void relu_ln_kernel(
    const float* __restrict__ pre, int nsplit, size_t splitStride,
    ushort* __restrict__ zb)
{
    int row = blockIdx.x;
    int tid = threadIdx.x;
    const float* p0 = pre + (size_t)row * PREDIM;
    ushort* zr = zb + (size_t)row * XDIM;

    // relu: cols 4*tid .. 4*tid+3   (256 threads x 4 = 1024)
    float4 v = *(const float4*)(p0 + 4 * tid);
    for (int s = 1; s < nsplit; ++s) {
        float4 w = *(const float4*)(p0 + s * splitStride + 4 * tid);
        v.x += w.x; v.y += w.y; v.z += w.z; v.w += w.w;
    }
    ushort4 o;
    o.x = f2bf(v.x > 0.f ? v.x : 0.f);
    o.y = f2bf(v.y > 0.f ? v.y : 0.f);
    o.z = f2bf(v.z > 0.f ? v.z : 0.f);
    o.w = f2bf(v.w > 0.f ? v.w : 0.f);
    *(ushort4*)(zr + 4 * tid) = o;

    __shared__ float warr[4][2];
    #pragma unroll
    for (int g = 0; g < 2; ++g) {
        int c = 1024 + g * 256 + tid;
        float xv = p0[c];
        for (int s = 1; s < nsplit; ++s) xv += p0[s * splitStride + c];
        float s = xv, s2 = xv * xv;
        #pragma unroll
        for (int off = 32; off; off >>= 1) {
            s  += __shfl_down(s, off);
            s2 += __shfl_down(s2, off);
        }
        int wave = tid >> 6, lane = tid & 63;
        if (lane == 0) { warr[wave][0] = s; warr[wave][1] = s2; }
        __syncthreads();
        float ts  = warr[0][0] + warr[1][0] + warr[2][0] + warr[3][0];
        float ts2 = warr[0][1] + warr[1][1] + warr[2][1] + warr[3][1];
        float mu  = ts * (1.0f / 256.0f);
        float var = ts2 * (1.0f / 256.0f) - mu * mu;
        float y = (xv - mu) * rsqrtf(var + 1e-5f);
        zr[c] = f2bf(y);
        __syncthreads();
    }
}

// ---------------------------------------------------------------------------
// MFMA attention. Block = (b,h) x q-chunk(64). 4 waves, 16 queries each.
// ---------------------------------------------------------------------------
__global__ __launch_bounds__(256) void attn_kernel(
    const ushort* __restrict__ qkvb, const int* __restrict__ seq_lens,
    ushort* __restrict__ zb)
{
    __shared__ ushort Kl[288 * 40];
    __shared__ ushort VTl[32 * 296];
    __shared__ ushort Pl[4][16 * 40];

    int bh = blockIdx.x;
    int b = bh >> 3, h = bh & 7;
    int kend = seq_lens[b] + 1; if (kend > TP) kend = TP;
    int tid = threadIdx.x;
    const size_t qbase = (size_t)(b * TP) * QKVDIM + h * 96;

    for (int idx = tid; idx < 31 * 32; idx += 256) {
        int row = 257 + (idx >> 5), d = idx & 31;
        Kl[row * 40 + d] = 0;
    }
    for (int idx = tid; idx < 32 * 32; idx += 256) {
        int d = idx >> 5, col = 257 + (idx & 31);
        VTl[d * 296 + col] = 0;
    }
    for (int idx = tid; idx < 257 * 4; idx += 256) {
        int row = idx >> 2, seg = idx & 3;
        *(bf16x8*)&Kl[row * 40 + seg * 8] =
            *(const bf16x8*)&qkvb[qbase + (size_t)row * QKVDIM + 32 + seg * 8];
    }
    for (int idx = tid; idx < 257 * 32; idx += 256) {
        int key = idx >> 5, d = idx & 31;
        VTl[d * 296 + key] = qkvb[qbase + (size_t)key * QKVDIM + 64 + d];
    }
    __syncthreads();

    int wave = tid >> 6, lane = tid & 63;
    int q0 = blockIdx.y * 64 + wave * 16;
    if (q0 > 256) return;
    int qcol = lane & 15, g = lane >> 4;
    int ktmax = (kend + 15) >> 4;
    const float scale = 0.17677669529663687f;

    int qg = q0 + qcol; if (qg > 256) qg = 256;
    bf16x8 aq = *(const bf16x8*)&qkvb[qbase + (size_t)qg * QKVDIM + g * 8];

    f32x4 s[17];
    const f32x4 zz = {};
    #pragma unroll
    for (int kt = 0; kt < 17; ++kt) {
        s[kt] = (f32x4)(-1e30f);
        if (kt < ktmax) {
            bf16x8 bk = *(const bf16x8*)&Kl[(kt * 16 + qcol) * 40 + g * 8];
            f32x4 r = __builtin_amdgcn_mfma_f32_16x16x32_bf16(aq, bk, zz, 0, 0, 0);
            bool kv = (kt * 16 + qcol) < kend;
            #pragma unroll
            for (int j = 0; j < 4; ++j)
                s[kt][j] = kv ? r[j] * scale : -1e30f;
        }
    }

    float m0[4], l0[4];
    #pragma unroll
    for (int j = 0; j < 4; ++j) m0[j] = -3.0e38f;
    #pragma unroll
    for (int kt = 0; kt < 17; ++kt)
        #pragma unroll
        for (int j = 0; j < 4; ++j) m0[j] = fmaxf(m0[j], s[kt][j]);
    #pragma unroll
    for (int j = 0; j < 4; ++j) {
        #pragma unroll
        for (int off = 1; off < 16; off <<= 1)
            m0[j] = fmaxf(m0[j], __shfl_xor(m0[j], off));
        l0[j] = 0.f;
    }
    #pragma unroll
    for (int kt = 0; kt < 17; ++kt)
        #pragma unroll
        for (int j = 0; j < 4; ++j) {
            float p = __expf(s[kt][j] - m0[j]);
            s[kt][j] = p;
            l0[j] += p;
        }
    #pragma unroll
    for (int j = 0; j < 4; ++j) {
        #pragma unroll
        for (int off = 1; off < 16; off <<= 1)
            l0[j] += __shfl_xor(l0[j], off);
        l0[j] = 1.0f / l0[j];
    }
    #pragma unroll
    for (int kt = 0; kt < 17; ++kt)
        #pragma unroll
        for (int j = 0; j < 4; ++j) s[kt][j] *= l0[j];

    f32x4 o[2] = {};
    ushort* Pw = Pl[wave];
    #pragma unroll
    for (int c = 0; c < 9; ++c) {
        if (c * 32 < kend) {
            #pragma unroll
            for (int t = 0; t < 2; ++t)
                #pragma unroll
                for (int j = 0; j < 4; ++j)
                    Pw[(g * 4 + j) * 40 + t * 16 + qcol] = f2bf(s[2 * c + t][j]);
            bf16x8 pa = *(const bf16x8*)&Pw[qcol * 40 + g * 8];
            #pragma unroll
            for (int n = 0; n < 2; ++n) {
                bf16x8 vb = *(const bf16x8*)&VTl[(n * 16 + qcol) * 296 + c * 32 + g * 8];
                o[n] = __builtin_amdgcn_mfma_f32_16x16x32_bf16(pa, vb, o[n], 0, 0, 0);
            }
        }
    }

    #pragma unroll
    for (int n = 0; n < 2; ++n)
        #pragma unroll
        for (int j = 0; j < 4; ++j) {
            int q = q0 + g * 4 + j;
            if (q <= 256)
                zb[(size_t)(b * TP + q) * XDIM + PREDIM + h * 32 + n * 16 + qcol] =
                    f2bf(o[n][j]);
        }
}

// ---------------------------------------------------------------------------
// out[b,c] = z[b,0,:1792] . W_cls[c,:] + b_cls[c]
// ---------------------------------------------------------------------------
__global__ __launch_bounds__(64) void cls_kernel(
    const ushort* __restrict__ zb, const float* __restrict__ W,
    const float* __restrict__ bias, float* __restrict__ out)
{
    int o = blockIdx.x;
    int c = o & 15, b = o >> 4;
    int lane = threadIdx.x;
    const ushort* zr = zb + (size_t)(b * TP) * XDIM;
    const float* wr = W + (size_t)c * ZDIM;
    float s = 0.f;
    for (int j = lane; j < ZDIM; j += 64) s += bf2f(zr[j]) * wr[j];
    #pragma unroll
    for (int off = 32; off; off >>= 1) s += __shfl_down(s, off);
    if (lane == 0) out[b * 16 + c] = s + bias[c];
}

// ---------------------------------------------------------------------------
extern "C" void kernel_launch(void* const* d_in, const int* in_sizes, int n_in,
                              void* d_out, int out_size, void* d_ws, size_t ws_size,
                              hipStream_t stream) {
    const int*   x        = (const int*)d_in[0];
    const int*   seq_lens = (const int*)d_in[1];
    const float* emb      = (const float*)d_in[2];
    const float* cls      = (const float*)d_in[3];
    const float* A        = (const float*)d_in[4];
    const float* A_qkv    = (const float*)d_in[5];
    const float* b        = (const float*)d_in[6];
    const float* W_cls    = (const float*)d_in[7];
    const float* b_cls    = (const float*)d_in[8];
    float* out = (float*)d_out;

    ushort* XbA  = (ushort*)d_ws;
    ushort* XbB  = XbA + (size_t)ROWS * XDIM;
    ushort* Ab   = XbB + (size_t)ROWS * XDIM;
    ushort* Aqb  = Ab + (size_t)PREDIM * 2048;
    float*  pre  = (float*)(Aqb + (size_t)QKVDIM * 512);
    ushort* qkvb = (ushort*)pre;   // overlapped: pre dead after relu_ln

    const size_t sstride = (size_t)ROWS * PREDIM;
    size_t base = (size_t)((char*)pre - (char*)d_ws);
    int nsplit = 1;
    if (ws_size >= base + 4 * sstride * sizeof(float)) nsplit = 4;
    else if (ws_size >= base + 2 * sstride * sizeof(float)) nsplit = 2;

    hipMemsetAsync(XbA, 0, (size_t)ROWS * XDIM * sizeof(ushort), stream);
    f2bf_kernel<<<(PREDIM * 2048 + 255) / 256, 256, 0, stream>>>(A, Ab, PREDIM * 2048);
    f2bf_kernel<<<(QKVDIM * 512 + 255) / 256, 256, 0, stream>>>(A_qkv, Aqb, QKVDIM * 512);
    build_u_kernel<<<ROWS, 256, 0, stream>>>(x, emb, cls, XbA, XbB);

    ushort* cur = XbA;
    ushort* nxt = XbB;
    for (int it = 0; it < 12; ++it) {
        // pre = [z | u] @ A^T + b  (split-K: 816 blocks at nsplit=4)
        gemm_bf16_kernel<<<dim3(17, 12, nsplit), 256, 0, stream>>>(
            cur, XDIM, Ab, b, pre, nullptr, PREDIM, ROWS, PREDIM,
            2048 / nsplit, 2048, sstride);
        relu_ln_kernel<<<ROWS, 256, 0, stream>>>(pre, nsplit, sstride, nxt);
        gemm_bf16_kernel<<<dim3(17, 6, 1), 256, 0, stream>>>(
            nxt + 1024, XDIM, Aqb, nullptr, nullptr, qkvb, QKVDIM, ROWS, QKVDIM,
            512, 512, 0);
        attn_kernel<<<dim3(64, 5), 256, 0, stream>>>(qkvb, seq_lens, nxt);
        ushort* tmp = cur; cur = nxt; nxt = tmp;
    }
    cls_kernel<<<128, 64, 0, stream>>>(cur, W_cls, b_cls, out);
}